// Round 15
// baseline (96.451 us; speedup 1.0000x reference)
//
#include <hip/hip_runtime.h>

// Chamfer distance, fp32 in/out, A,B = [4][8192][3], via bf16-split MFMA.
// Embedding (HW-validated R4-R14, absmax 0.0): d^2(u,v) = rw(u).cw(v), K=15:
//  rw: s2h s2l s2ll 1 1 1 | mxh myh mzh | mxh myh mzh | mxl myl mzl | 0
//  cw: 1 1 1 s2h s2l s2ll |  xh  yh  zh |  xl  yl  zl |  xh  yh  zh | 0
// Swapped operands: streamed opposite-set points are MFMA-A (min axis ->
// lane-local in D), resident points are MFMA-B; fminf tree16 -> v_min3.
// R15 = R14's min kernel (FRAGS=8, SSPLIT=4, 1024 blocks = 4/CU, XCD swizzle,
// setprio, 2-chain, DEPTH=4 ring -- best measured) + LAST-BLOCK FUSED REDUCE:
// completion counter (reset by prep), release fence + syncthreads + atomicAdd;
// last block acquire-fences and does the 256KB sqrt-sum in-kernel.
// 2 dispatches total.

typedef __bf16 bf16x8 __attribute__((ext_vector_type(8)));
typedef float f32x16 __attribute__((ext_vector_type(16)));
typedef unsigned short u16;

constexpr int NB = 4;
constexpr int NPTS = 8192;
constexpr int NROWS = 2 * NB * NPTS;            // 65536
constexpr int FRAGS = 8;                        // resident frags -> 256 rows/block
constexpr int ROWS_PER_BLK = FRAGS * 32;        // 256
constexpr int ROWBLKS = NPTS / ROWS_PER_BLK;    // 32
constexpr int SSPLIT = 4;                       // stream split -> 1024 blocks
constexpr int SPTS = NPTS / SSPLIT;             // 2048 streamed pts/block
constexpr int TILES_PER_WAVE = SPTS / 32 / 4;   // 16
constexpr int DEPTH = 4;                        // prefetch ring (R8-proven)
constexpr int NBLOCKS = 2 * NB * ROWBLKS * SSPLIT;  // 1024

// ws: streamT(rw) 2MB @0 | resT(cw) 2MB @2MB | ws_min 256KB @4MB | counter @+256KB
constexpr size_t REST_OFF = 2u << 20;
constexpr size_t WSMIN_OFF = 4u << 20;
constexpr size_t CNT_OFF = (4u << 20) + (256u << 10);

__device__ __forceinline__ float bsplit(float x, u16& hbits, float& hf) {
    unsigned u = __float_as_uint(x);
    unsigned r = (u + 0x7FFFu + ((u >> 16) & 1u)) & 0xFFFF0000u;  // RTNE bf16
    hbits = (u16)(r >> 16);
    hf = __uint_as_float(r);
    return x - hf;   // exact
}

__global__ __launch_bounds__(256)
void chamfer_prep_kernel(const float* __restrict__ A, const float* __restrict__ B,
                         u16* __restrict__ streamT, u16* __restrict__ resT,
                         unsigned int* __restrict__ ws_min,
                         unsigned int* __restrict__ counter,
                         float* __restrict__ out) {
    int idx = blockIdx.x * 256 + threadIdx.x;       // 0..65535
    if (idx == 0) { counter[0] = 0u; out[0] = 0.0f; }
    int pt = idx & (NPTS - 1);
    int batch = (idx >> 13) & (NB - 1);
    int set = idx >> 15;                             // 0=A, 1=B
    const float* src = (set ? B : A) + ((size_t)batch * NPTS + pt) * 3;
    float x = src[0], y = src[1], z = src[2];
    float s2 = fmaf(x, x, fmaf(y, y, z * z));
    float hf, h2;
    u16 s2h, s2l, s2ll, xh, xl, yh, yl, zh, zl, mxh, mxl, myh, myl, mzh, mzl;
    float r1 = bsplit(s2, s2h, hf);
    float r2 = bsplit(r1, s2l, h2);
    bsplit(r2, s2ll, h2);
    float t;
    t = bsplit(x, xh, hf);          bsplit(t, xl, h2);
    t = bsplit(y, yh, hf);          bsplit(t, yl, h2);
    t = bsplit(z, zh, hf);          bsplit(t, zl, h2);
    t = bsplit(-2.0f * x, mxh, hf); bsplit(t, mxl, h2);
    t = bsplit(-2.0f * y, myh, hf); bsplit(t, myl, h2);
    t = bsplit(-2.0f * z, mzh, hf); bsplit(t, mzl, h2);
    const unsigned ONE = 0x3F80u;
    #define PK(a, b) ((unsigned)(a) | ((unsigned)(b) << 16))
    uint4 rw0 = make_uint4(PK(s2h, s2l), PK(s2ll, ONE), PK(ONE, ONE), PK(mxh, myh));
    uint4 rw1 = make_uint4(PK(mzh, mxh), PK(myh, mzh), PK(mxl, myl), PK(mzl, 0));
    uint4 cw0 = make_uint4(PK(ONE, ONE), PK(ONE, s2h), PK(s2l, s2ll), PK(xh, yh));
    uint4 cw1 = make_uint4(PK(zh, xl), PK(yl, zl), PK(xh, yh), PK(zh, 0));
    #undef PK
    uint4* sp = (uint4*)(streamT + (size_t)idx * 16);
    uint4* rp = (uint4*)(resT + (size_t)idx * 16);
    sp[0] = rw0; sp[1] = rw1;
    rp[0] = cw0; rp[1] = cw1;
    ws_min[idx] = 0xFFFFFFFFu;
}

__device__ __forceinline__ float tree16acc(const f32x16& d, float acc) {
    float m0 = fminf(fminf(d[0],  d[1]),  d[2]);    // -> v_min3 (clang fuses)
    float m1 = fminf(fminf(d[3],  d[4]),  d[5]);
    float m2 = fminf(fminf(d[6],  d[7]),  d[8]);
    float m3 = fminf(fminf(d[9],  d[10]), d[11]);
    float m4 = fminf(fminf(d[12], d[13]), d[14]);
    float n0 = fminf(fminf(m0, m1), m2);
    float n1 = fminf(fminf(m3, m4), d[15]);
    return fminf(fminf(n0, n1), acc);
}

__global__ __launch_bounds__(256, 4)
void chamfer_minmfma_kernel(const u16* __restrict__ streamT,
                            const u16* __restrict__ resT,
                            unsigned int* __restrict__ ws_min,
                            unsigned int* __restrict__ counter,
                            float* __restrict__ out) {
    constexpr float SCALE = 1.0f / (NB * NPTS * 12.8f);
    // XCD swizzle: low 3 bits = dir*NB+batch, so all blocks sharing one
    // (dir,batch) tuple table land on one XCD (round-robin %8 dispatch).
    int db     = blockIdx.x & 7;
    int rest   = blockIdx.x >> 3;
    int split  = rest & (SSPLIT - 1);
    int rowblk = rest >> 2;                  // 0..ROWBLKS-1
    int batch  = db & (NB - 1);
    int dir    = db >> 2;

    int lane = threadIdx.x & 63;
    int wave = threadIdx.x >> 6;
    int l31 = lane & 31, lh = lane >> 5;

    // Resident B-operand: this block's 256 output points (cw vectors).
    const u16* rbase = resT + (((size_t)(dir * NB + batch) * NPTS) + rowblk * ROWS_PER_BLK) * 16;
    bf16x8 res0 = *(const bf16x8*)(rbase + (0 * 32 + l31) * 16 + lh * 8);
    bf16x8 res1 = *(const bf16x8*)(rbase + (1 * 32 + l31) * 16 + lh * 8);
    bf16x8 res2 = *(const bf16x8*)(rbase + (2 * 32 + l31) * 16 + lh * 8);
    bf16x8 res3 = *(const bf16x8*)(rbase + (3 * 32 + l31) * 16 + lh * 8);
    bf16x8 res4 = *(const bf16x8*)(rbase + (4 * 32 + l31) * 16 + lh * 8);
    bf16x8 res5 = *(const bf16x8*)(rbase + (5 * 32 + l31) * 16 + lh * 8);
    bf16x8 res6 = *(const bf16x8*)(rbase + (6 * 32 + l31) * 16 + lh * 8);
    bf16x8 res7 = *(const bf16x8*)(rbase + (7 * 32 + l31) * 16 + lh * 8);

    // Stream A-operand: opposite set, this block's split, wave-partitioned.
    const uint4* wp = (const uint4*)streamT
                    + (size_t)((dir ^ 1) * NB + batch) * NPTS * 2
                    + (size_t)split * SPTS * 2
                    + (size_t)wave * TILES_PER_WAVE * 64
                    + (l31 * 2 + lh);

    f32x16 zf;
    #pragma unroll
    for (int j = 0; j < 16; ++j) zf[j] = 0.0f;
    float acc0 = 3.0e38f, acc1 = 3.0e38f, acc2 = 3.0e38f, acc3 = 3.0e38f;
    float acc4 = 3.0e38f, acc5 = 3.0e38f, acc6 = 3.0e38f, acc7 = 3.0e38f;

    uint4 pipe[DEPTH];
    #pragma unroll
    for (int i = 0; i < DEPTH; ++i) pipe[i] = wp[i * 64];

    // R8-proven shape: rotating DEPTH=4 ring, outer loop NOT unrolled.
    // 2-chain MFMA pipeline: only dA,dB (32 VGPRs) live at once.
    for (int t = 0; t < TILES_PER_WAVE; t += DEPTH) {
        #pragma unroll
        for (int u = 0; u < DEPTH; ++u) {
            uint4 cur = pipe[u];
            // Tail prefetch overreads into resT region: valid memory, never used.
            pipe[u] = wp[(t + u + DEPTH) * 64];
            bf16x8 aop = __builtin_bit_cast(bf16x8, cur);
            __builtin_amdgcn_s_setprio(1);
            f32x16 dA = __builtin_amdgcn_mfma_f32_32x32x16_bf16(aop, res0, zf, 0, 0, 0);
            f32x16 dB = __builtin_amdgcn_mfma_f32_32x32x16_bf16(aop, res1, zf, 0, 0, 0);
            acc0 = tree16acc(dA, acc0);
            dA = __builtin_amdgcn_mfma_f32_32x32x16_bf16(aop, res2, zf, 0, 0, 0);
            acc1 = tree16acc(dB, acc1);
            dB = __builtin_amdgcn_mfma_f32_32x32x16_bf16(aop, res3, zf, 0, 0, 0);
            acc2 = tree16acc(dA, acc2);
            dA = __builtin_amdgcn_mfma_f32_32x32x16_bf16(aop, res4, zf, 0, 0, 0);
            acc3 = tree16acc(dB, acc3);
            dB = __builtin_amdgcn_mfma_f32_32x32x16_bf16(aop, res5, zf, 0, 0, 0);
            acc4 = tree16acc(dA, acc4);
            dA = __builtin_amdgcn_mfma_f32_32x32x16_bf16(aop, res6, zf, 0, 0, 0);
            acc5 = tree16acc(dB, acc5);
            dB = __builtin_amdgcn_mfma_f32_32x32x16_bf16(aop, res7, zf, 0, 0, 0);
            acc6 = tree16acc(dA, acc6);
            acc7 = tree16acc(dB, acc7);
            __builtin_amdgcn_s_setprio(0);
        }
    }

    // Fold lh halves (lane and lane^32 hold complementary stream rows of the
    // same resident col), then one atomicMin per resident row per wave.
    unsigned int* wout = ws_min + (size_t)(dir * NB + batch) * NPTS + rowblk * ROWS_PER_BLK;
    float accs[FRAGS] = {acc0, acc1, acc2, acc3, acc4, acc5, acc6, acc7};
    #pragma unroll
    for (int f = 0; f < FRAGS; ++f) {
        float v = fminf(accs[f], __shfl_xor(accs[f], 32, 64));
        v = fmaxf(v, 0.0f);   // >= 0: uint order == float order
        if (lh == 0) atomicMin(&wout[f * 32 + l31], __float_as_uint(v));
    }

    // ---- Last-block fused reduce ----
    __shared__ unsigned int lastFlag;
    __shared__ float redl[4];
    __threadfence();                     // release: mins visible device-wide
    __syncthreads();                     // drains mem ops; all fences done
    if (threadIdx.x == 0)
        lastFlag = (atomicAdd(counter, 1u) == (unsigned)(NBLOCKS - 1)) ? 1u : 0u;
    __syncthreads();
    if (lastFlag == 0u) return;

    __threadfence();                     // acquire: see all blocks' mins
    const uint4* p = (const uint4*)ws_min;   // 16384 uint4
    float s = 0.0f;
    #pragma unroll 8
    for (int k = 0; k < 64; ++k) {
        uint4 v = p[threadIdx.x + k * 256];
        s += sqrtf(__uint_as_float(v.x)) + sqrtf(__uint_as_float(v.y))
           + sqrtf(__uint_as_float(v.z)) + sqrtf(__uint_as_float(v.w));
    }
    #pragma unroll
    for (int off = 32; off >= 1; off >>= 1) s += __shfl_down(s, off, 64);
    if ((threadIdx.x & 63) == 0) redl[threadIdx.x >> 6] = s;
    __syncthreads();
    if (threadIdx.x == 0)
        out[0] = (redl[0] + redl[1] + redl[2] + redl[3]) * SCALE;
}

extern "C" void kernel_launch(void* const* d_in, const int* in_sizes, int n_in,
                              void* d_out, int out_size, void* d_ws, size_t ws_size,
                              hipStream_t stream) {
    const float* A = (const float*)d_in[0];
    const float* B = (const float*)d_in[1];
    float* out = (float*)d_out;
    u16* streamT = (u16*)d_ws;
    u16* resT = (u16*)((char*)d_ws + REST_OFF);
    unsigned int* wsm = (unsigned int*)((char*)d_ws + WSMIN_OFF);
    unsigned int* cnt = (unsigned int*)((char*)d_ws + CNT_OFF);

    chamfer_prep_kernel<<<NROWS / 256, 256, 0, stream>>>(A, B, streamT, resT, wsm, cnt, out);
    chamfer_minmfma_kernel<<<NBLOCKS, 256, 0, stream>>>(streamT, resT, wsm, cnt, out);
}

// Round 16
// 30.454 us; speedup vs baseline: 3.1671x; 3.1671x over previous
//
#include <hip/hip_runtime.h>

// Chamfer distance, fp32 in/out, A,B = [4][8192][3], via bf16-split MFMA.
// Embedding (HW-validated R4-R15, absmax 0.0): d^2(u,v) = rw(u).cw(v), K=15:
//  rw: s2h s2l s2ll 1 1 1 | mxh myh mzh | mxh myh mzh | mxl myl mzl | 0
//  cw: 1 1 1 s2h s2l s2ll |  xh  yh  zh |  xl  yl  zl |  xh  yh  zh | 0
// Swapped operands: streamed opposite-set points are MFMA-A (min axis ->
// lane-local in D), resident points are MFMA-B; fminf tree16 -> v_min3.
// R16 = R14's min kernel main loop VERBATIM (FRAGS=8, SSPLIT=4, 1024 blocks,
// XCD swizzle, setprio, 2-chain, DEPTH=4 ring) with the atomicMin epilogue
// replaced by R13's proven LDS cross-wave merge + coalesced plain stores into
// per-split slices ws_min[SSPLIT][NROWS]; reduce takes the 4-way split min.
// No atomics in the min kernel; prep no longer inits ws_min.

typedef __bf16 bf16x8 __attribute__((ext_vector_type(8)));
typedef float f32x16 __attribute__((ext_vector_type(16)));
typedef unsigned short u16;

constexpr int NB = 4;
constexpr int NPTS = 8192;
constexpr int NROWS = 2 * NB * NPTS;            // 65536
constexpr int FRAGS = 8;                        // resident frags -> 256 rows/block
constexpr int ROWS_PER_BLK = FRAGS * 32;        // 256
constexpr int ROWBLKS = NPTS / ROWS_PER_BLK;    // 32
constexpr int SSPLIT = 4;                       // stream split -> 1024 blocks
constexpr int SPTS = NPTS / SSPLIT;             // 2048 streamed pts/block
constexpr int TILES_PER_WAVE = SPTS / 32 / 4;   // 16
constexpr int DEPTH = 4;                        // prefetch ring (R8-proven)

// ws: streamT(rw) 2MB @0 | resT(cw) 2MB @2MB | ws_min[SSPLIT][NROWS] 1MB @4MB
constexpr size_t REST_OFF = 2u << 20;
constexpr size_t WSMIN_OFF = 4u << 20;

__device__ __forceinline__ float bsplit(float x, u16& hbits, float& hf) {
    unsigned u = __float_as_uint(x);
    unsigned r = (u + 0x7FFFu + ((u >> 16) & 1u)) & 0xFFFF0000u;  // RTNE bf16
    hbits = (u16)(r >> 16);
    hf = __uint_as_float(r);
    return x - hf;   // exact
}

__global__ __launch_bounds__(256)
void chamfer_prep_kernel(const float* __restrict__ A, const float* __restrict__ B,
                         u16* __restrict__ streamT, u16* __restrict__ resT,
                         float* __restrict__ out) {
    int idx = blockIdx.x * 256 + threadIdx.x;       // 0..65535
    if (idx == 0) out[0] = 0.0f;                    // replaces d_out memset
    int pt = idx & (NPTS - 1);
    int batch = (idx >> 13) & (NB - 1);
    int set = idx >> 15;                             // 0=A, 1=B
    const float* src = (set ? B : A) + ((size_t)batch * NPTS + pt) * 3;
    float x = src[0], y = src[1], z = src[2];
    float s2 = fmaf(x, x, fmaf(y, y, z * z));
    float hf, h2;
    u16 s2h, s2l, s2ll, xh, xl, yh, yl, zh, zl, mxh, mxl, myh, myl, mzh, mzl;
    float r1 = bsplit(s2, s2h, hf);
    float r2 = bsplit(r1, s2l, h2);
    bsplit(r2, s2ll, h2);
    float t;
    t = bsplit(x, xh, hf);          bsplit(t, xl, h2);
    t = bsplit(y, yh, hf);          bsplit(t, yl, h2);
    t = bsplit(z, zh, hf);          bsplit(t, zl, h2);
    t = bsplit(-2.0f * x, mxh, hf); bsplit(t, mxl, h2);
    t = bsplit(-2.0f * y, myh, hf); bsplit(t, myl, h2);
    t = bsplit(-2.0f * z, mzh, hf); bsplit(t, mzl, h2);
    const unsigned ONE = 0x3F80u;
    #define PK(a, b) ((unsigned)(a) | ((unsigned)(b) << 16))
    uint4 rw0 = make_uint4(PK(s2h, s2l), PK(s2ll, ONE), PK(ONE, ONE), PK(mxh, myh));
    uint4 rw1 = make_uint4(PK(mzh, mxh), PK(myh, mzh), PK(mxl, myl), PK(mzl, 0));
    uint4 cw0 = make_uint4(PK(ONE, ONE), PK(ONE, s2h), PK(s2l, s2ll), PK(xh, yh));
    uint4 cw1 = make_uint4(PK(zh, xl), PK(yl, zl), PK(xh, yh), PK(zh, 0));
    #undef PK
    uint4* sp = (uint4*)(streamT + (size_t)idx * 16);
    uint4* rp = (uint4*)(resT + (size_t)idx * 16);
    sp[0] = rw0; sp[1] = rw1;
    rp[0] = cw0; rp[1] = cw1;
}

__device__ __forceinline__ float tree16acc(const f32x16& d, float acc) {
    float m0 = fminf(fminf(d[0],  d[1]),  d[2]);    // -> v_min3 (clang fuses)
    float m1 = fminf(fminf(d[3],  d[4]),  d[5]);
    float m2 = fminf(fminf(d[6],  d[7]),  d[8]);
    float m3 = fminf(fminf(d[9],  d[10]), d[11]);
    float m4 = fminf(fminf(d[12], d[13]), d[14]);
    float n0 = fminf(fminf(m0, m1), m2);
    float n1 = fminf(fminf(m3, m4), d[15]);
    return fminf(fminf(n0, n1), acc);
}

__global__ __launch_bounds__(256, 4)
void chamfer_minmfma_kernel(const u16* __restrict__ streamT,
                            const u16* __restrict__ resT,
                            unsigned int* __restrict__ ws_min) {
    // XCD swizzle: low 3 bits = dir*NB+batch, so all blocks sharing one
    // (dir,batch) tuple table land on one XCD (round-robin %8 dispatch).
    int db     = blockIdx.x & 7;
    int rest   = blockIdx.x >> 3;
    int split  = rest & (SSPLIT - 1);
    int rowblk = rest >> 2;                  // 0..ROWBLKS-1
    int batch  = db & (NB - 1);
    int dir    = db >> 2;

    int lane = threadIdx.x & 63;
    int wave = threadIdx.x >> 6;
    int l31 = lane & 31, lh = lane >> 5;

    // Resident B-operand: this block's 256 output points (cw vectors).
    const u16* rbase = resT + (((size_t)(dir * NB + batch) * NPTS) + rowblk * ROWS_PER_BLK) * 16;
    bf16x8 res0 = *(const bf16x8*)(rbase + (0 * 32 + l31) * 16 + lh * 8);
    bf16x8 res1 = *(const bf16x8*)(rbase + (1 * 32 + l31) * 16 + lh * 8);
    bf16x8 res2 = *(const bf16x8*)(rbase + (2 * 32 + l31) * 16 + lh * 8);
    bf16x8 res3 = *(const bf16x8*)(rbase + (3 * 32 + l31) * 16 + lh * 8);
    bf16x8 res4 = *(const bf16x8*)(rbase + (4 * 32 + l31) * 16 + lh * 8);
    bf16x8 res5 = *(const bf16x8*)(rbase + (5 * 32 + l31) * 16 + lh * 8);
    bf16x8 res6 = *(const bf16x8*)(rbase + (6 * 32 + l31) * 16 + lh * 8);
    bf16x8 res7 = *(const bf16x8*)(rbase + (7 * 32 + l31) * 16 + lh * 8);

    // Stream A-operand: opposite set, this block's split, wave-partitioned.
    const uint4* wp = (const uint4*)streamT
                    + (size_t)((dir ^ 1) * NB + batch) * NPTS * 2
                    + (size_t)split * SPTS * 2
                    + (size_t)wave * TILES_PER_WAVE * 64
                    + (l31 * 2 + lh);

    f32x16 zf;
    #pragma unroll
    for (int j = 0; j < 16; ++j) zf[j] = 0.0f;
    float acc0 = 3.0e38f, acc1 = 3.0e38f, acc2 = 3.0e38f, acc3 = 3.0e38f;
    float acc4 = 3.0e38f, acc5 = 3.0e38f, acc6 = 3.0e38f, acc7 = 3.0e38f;

    uint4 pipe[DEPTH];
    #pragma unroll
    for (int i = 0; i < DEPTH; ++i) pipe[i] = wp[i * 64];

    // R8-proven shape: rotating DEPTH=4 ring, outer loop NOT unrolled.
    // 2-chain MFMA pipeline: only dA,dB (32 VGPRs) live at once.
    for (int t = 0; t < TILES_PER_WAVE; t += DEPTH) {
        #pragma unroll
        for (int u = 0; u < DEPTH; ++u) {
            uint4 cur = pipe[u];
            // Tail prefetch overreads into resT region: valid memory, never used.
            pipe[u] = wp[(t + u + DEPTH) * 64];
            bf16x8 aop = __builtin_bit_cast(bf16x8, cur);
            __builtin_amdgcn_s_setprio(1);
            f32x16 dA = __builtin_amdgcn_mfma_f32_32x32x16_bf16(aop, res0, zf, 0, 0, 0);
            f32x16 dB = __builtin_amdgcn_mfma_f32_32x32x16_bf16(aop, res1, zf, 0, 0, 0);
            acc0 = tree16acc(dA, acc0);
            dA = __builtin_amdgcn_mfma_f32_32x32x16_bf16(aop, res2, zf, 0, 0, 0);
            acc1 = tree16acc(dB, acc1);
            dB = __builtin_amdgcn_mfma_f32_32x32x16_bf16(aop, res3, zf, 0, 0, 0);
            acc2 = tree16acc(dA, acc2);
            dA = __builtin_amdgcn_mfma_f32_32x32x16_bf16(aop, res4, zf, 0, 0, 0);
            acc3 = tree16acc(dB, acc3);
            dB = __builtin_amdgcn_mfma_f32_32x32x16_bf16(aop, res5, zf, 0, 0, 0);
            acc4 = tree16acc(dA, acc4);
            dA = __builtin_amdgcn_mfma_f32_32x32x16_bf16(aop, res6, zf, 0, 0, 0);
            acc5 = tree16acc(dB, acc5);
            dB = __builtin_amdgcn_mfma_f32_32x32x16_bf16(aop, res7, zf, 0, 0, 0);
            acc6 = tree16acc(dA, acc6);
            acc7 = tree16acc(dB, acc7);
            __builtin_amdgcn_s_setprio(0);
        }
    }

    // Fold lh halves (lane and lane^32 hold complementary stream rows of the
    // same resident col); cross-wave LDS merge (R13-proven epilogue); one
    // coalesced plain store per block into this split's slice. No atomics.
    float accs[FRAGS] = {acc0, acc1, acc2, acc3, acc4, acc5, acc6, acc7};
    #pragma unroll
    for (int f = 0; f < FRAGS; ++f)
        accs[f] = fminf(accs[f], __shfl_xor(accs[f], 32, 64));

    __shared__ float part[4][ROWS_PER_BLK];
    if (lh == 0) {
        #pragma unroll
        for (int f = 0; f < FRAGS; ++f) part[wave][f * 32 + l31] = accs[f];
    }
    __syncthreads();
    int tid = threadIdx.x;
    float m = fminf(fminf(part[0][tid], part[1][tid]),
                    fminf(part[2][tid], part[3][tid]));
    unsigned int* wout = ws_min + (size_t)split * NROWS
                       + (size_t)(dir * NB + batch) * NPTS + rowblk * ROWS_PER_BLK;
    wout[tid] = __float_as_uint(fmaxf(m, 0.0f));
}

__global__ __launch_bounds__(256)
void chamfer_reduce_kernel(const unsigned int* __restrict__ ws_min,
                           float* __restrict__ out) {
    constexpr float SCALE = 1.0f / (NB * NPTS * 12.8f);
    int idx = (blockIdx.x * 256 + threadIdx.x) * 4;
    uint4 v0 = *(const uint4*)(ws_min + idx);
    uint4 v1 = *(const uint4*)(ws_min + 1 * NROWS + idx);
    uint4 v2 = *(const uint4*)(ws_min + 2 * NROWS + idx);
    uint4 v3 = *(const uint4*)(ws_min + 3 * NROWS + idx);
    float mx = fminf(fminf(__uint_as_float(v0.x), __uint_as_float(v1.x)),
                     fminf(__uint_as_float(v2.x), __uint_as_float(v3.x)));
    float my = fminf(fminf(__uint_as_float(v0.y), __uint_as_float(v1.y)),
                     fminf(__uint_as_float(v2.y), __uint_as_float(v3.y)));
    float mz = fminf(fminf(__uint_as_float(v0.z), __uint_as_float(v1.z)),
                     fminf(__uint_as_float(v2.z), __uint_as_float(v3.z)));
    float mw = fminf(fminf(__uint_as_float(v0.w), __uint_as_float(v1.w)),
                     fminf(__uint_as_float(v2.w), __uint_as_float(v3.w)));
    float s = sqrtf(mx) + sqrtf(my) + sqrtf(mz) + sqrtf(mw);
    #pragma unroll
    for (int off = 32; off >= 1; off >>= 1) s += __shfl_down(s, off, 64);
    __shared__ float redl[4];
    if ((threadIdx.x & 63) == 0) redl[threadIdx.x >> 6] = s;
    __syncthreads();
    if (threadIdx.x == 0)
        atomicAdd(out, (redl[0] + redl[1] + redl[2] + redl[3]) * SCALE);
}

extern "C" void kernel_launch(void* const* d_in, const int* in_sizes, int n_in,
                              void* d_out, int out_size, void* d_ws, size_t ws_size,
                              hipStream_t stream) {
    const float* A = (const float*)d_in[0];
    const float* B = (const float*)d_in[1];
    float* out = (float*)d_out;
    u16* streamT = (u16*)d_ws;
    u16* resT = (u16*)((char*)d_ws + REST_OFF);
    unsigned int* wsm = (unsigned int*)((char*)d_ws + WSMIN_OFF);

    chamfer_prep_kernel<<<NROWS / 256, 256, 0, stream>>>(A, B, streamT, resT, out);
    chamfer_minmfma_kernel<<<2 * NB * ROWBLKS * SSPLIT, 256, 0, stream>>>(streamT, resT, wsm);
    chamfer_reduce_kernel<<<NROWS / 4 / 256, 256, 0, stream>>>(wsm, out);
}

// Round 17
// 29.500 us; speedup vs baseline: 3.2695x; 1.0323x over previous
//
#include <hip/hip_runtime.h>

// Chamfer distance, fp32 in/out, A,B = [4][8192][3], via bf16-split MFMA.
// Embedding (HW-validated R4-R16, absmax 0.0): d^2(u,v) = rw(u).cw(v), K=15:
//  rw: s2h s2l s2ll 1 1 1 | mxh myh mzh | mxh myh mzh | mxl myl mzl | 0
//  cw: 1 1 1 s2h s2l s2ll |  xh  yh  zh |  xl  yl  zl |  xh  yh  zh | 0
// Swapped operands: streamed opposite-set points are MFMA-A (min axis ->
// lane-local in D), resident points are MFMA-B; fminf tree16 -> v_min3.
// R17 = R16 byte-identical minus s_setprio (isolating it: no wave role-split
// here -> T5 prerequisite absent; suspected per-tile scheduling fence).

typedef __bf16 bf16x8 __attribute__((ext_vector_type(8)));
typedef float f32x16 __attribute__((ext_vector_type(16)));
typedef unsigned short u16;

constexpr int NB = 4;
constexpr int NPTS = 8192;
constexpr int NROWS = 2 * NB * NPTS;            // 65536
constexpr int FRAGS = 8;                        // resident frags -> 256 rows/block
constexpr int ROWS_PER_BLK = FRAGS * 32;        // 256
constexpr int ROWBLKS = NPTS / ROWS_PER_BLK;    // 32
constexpr int SSPLIT = 4;                       // stream split -> 1024 blocks
constexpr int SPTS = NPTS / SSPLIT;             // 2048 streamed pts/block
constexpr int TILES_PER_WAVE = SPTS / 32 / 4;   // 16
constexpr int DEPTH = 4;                        // prefetch ring (R8-proven)

// ws: streamT(rw) 2MB @0 | resT(cw) 2MB @2MB | ws_min[SSPLIT][NROWS] 1MB @4MB
constexpr size_t REST_OFF = 2u << 20;
constexpr size_t WSMIN_OFF = 4u << 20;

__device__ __forceinline__ float bsplit(float x, u16& hbits, float& hf) {
    unsigned u = __float_as_uint(x);
    unsigned r = (u + 0x7FFFu + ((u >> 16) & 1u)) & 0xFFFF0000u;  // RTNE bf16
    hbits = (u16)(r >> 16);
    hf = __uint_as_float(r);
    return x - hf;   // exact
}

__global__ __launch_bounds__(256)
void chamfer_prep_kernel(const float* __restrict__ A, const float* __restrict__ B,
                         u16* __restrict__ streamT, u16* __restrict__ resT,
                         float* __restrict__ out) {
    int idx = blockIdx.x * 256 + threadIdx.x;       // 0..65535
    if (idx == 0) out[0] = 0.0f;                    // replaces d_out memset
    int pt = idx & (NPTS - 1);
    int batch = (idx >> 13) & (NB - 1);
    int set = idx >> 15;                             // 0=A, 1=B
    const float* src = (set ? B : A) + ((size_t)batch * NPTS + pt) * 3;
    float x = src[0], y = src[1], z = src[2];
    float s2 = fmaf(x, x, fmaf(y, y, z * z));
    float hf, h2;
    u16 s2h, s2l, s2ll, xh, xl, yh, yl, zh, zl, mxh, mxl, myh, myl, mzh, mzl;
    float r1 = bsplit(s2, s2h, hf);
    float r2 = bsplit(r1, s2l, h2);
    bsplit(r2, s2ll, h2);
    float t;
    t = bsplit(x, xh, hf);          bsplit(t, xl, h2);
    t = bsplit(y, yh, hf);          bsplit(t, yl, h2);
    t = bsplit(z, zh, hf);          bsplit(t, zl, h2);
    t = bsplit(-2.0f * x, mxh, hf); bsplit(t, mxl, h2);
    t = bsplit(-2.0f * y, myh, hf); bsplit(t, myl, h2);
    t = bsplit(-2.0f * z, mzh, hf); bsplit(t, mzl, h2);
    const unsigned ONE = 0x3F80u;
    #define PK(a, b) ((unsigned)(a) | ((unsigned)(b) << 16))
    uint4 rw0 = make_uint4(PK(s2h, s2l), PK(s2ll, ONE), PK(ONE, ONE), PK(mxh, myh));
    uint4 rw1 = make_uint4(PK(mzh, mxh), PK(myh, mzh), PK(mxl, myl), PK(mzl, 0));
    uint4 cw0 = make_uint4(PK(ONE, ONE), PK(ONE, s2h), PK(s2l, s2ll), PK(xh, yh));
    uint4 cw1 = make_uint4(PK(zh, xl), PK(yl, zl), PK(xh, yh), PK(zh, 0));
    #undef PK
    uint4* sp = (uint4*)(streamT + (size_t)idx * 16);
    uint4* rp = (uint4*)(resT + (size_t)idx * 16);
    sp[0] = rw0; sp[1] = rw1;
    rp[0] = cw0; rp[1] = cw1;
}

__device__ __forceinline__ float tree16acc(const f32x16& d, float acc) {
    float m0 = fminf(fminf(d[0],  d[1]),  d[2]);    // -> v_min3 (clang fuses)
    float m1 = fminf(fminf(d[3],  d[4]),  d[5]);
    float m2 = fminf(fminf(d[6],  d[7]),  d[8]);
    float m3 = fminf(fminf(d[9],  d[10]), d[11]);
    float m4 = fminf(fminf(d[12], d[13]), d[14]);
    float n0 = fminf(fminf(m0, m1), m2);
    float n1 = fminf(fminf(m3, m4), d[15]);
    return fminf(fminf(n0, n1), acc);
}

__global__ __launch_bounds__(256, 4)
void chamfer_minmfma_kernel(const u16* __restrict__ streamT,
                            const u16* __restrict__ resT,
                            unsigned int* __restrict__ ws_min) {
    // XCD swizzle: low 3 bits = dir*NB+batch, so all blocks sharing one
    // (dir,batch) tuple table land on one XCD (round-robin %8 dispatch).
    int db     = blockIdx.x & 7;
    int rest   = blockIdx.x >> 3;
    int split  = rest & (SSPLIT - 1);
    int rowblk = rest >> 2;                  // 0..ROWBLKS-1
    int batch  = db & (NB - 1);
    int dir    = db >> 2;

    int lane = threadIdx.x & 63;
    int wave = threadIdx.x >> 6;
    int l31 = lane & 31, lh = lane >> 5;

    // Resident B-operand: this block's 256 output points (cw vectors).
    const u16* rbase = resT + (((size_t)(dir * NB + batch) * NPTS) + rowblk * ROWS_PER_BLK) * 16;
    bf16x8 res0 = *(const bf16x8*)(rbase + (0 * 32 + l31) * 16 + lh * 8);
    bf16x8 res1 = *(const bf16x8*)(rbase + (1 * 32 + l31) * 16 + lh * 8);
    bf16x8 res2 = *(const bf16x8*)(rbase + (2 * 32 + l31) * 16 + lh * 8);
    bf16x8 res3 = *(const bf16x8*)(rbase + (3 * 32 + l31) * 16 + lh * 8);
    bf16x8 res4 = *(const bf16x8*)(rbase + (4 * 32 + l31) * 16 + lh * 8);
    bf16x8 res5 = *(const bf16x8*)(rbase + (5 * 32 + l31) * 16 + lh * 8);
    bf16x8 res6 = *(const bf16x8*)(rbase + (6 * 32 + l31) * 16 + lh * 8);
    bf16x8 res7 = *(const bf16x8*)(rbase + (7 * 32 + l31) * 16 + lh * 8);

    // Stream A-operand: opposite set, this block's split, wave-partitioned.
    const uint4* wp = (const uint4*)streamT
                    + (size_t)((dir ^ 1) * NB + batch) * NPTS * 2
                    + (size_t)split * SPTS * 2
                    + (size_t)wave * TILES_PER_WAVE * 64
                    + (l31 * 2 + lh);

    f32x16 zf;
    #pragma unroll
    for (int j = 0; j < 16; ++j) zf[j] = 0.0f;
    float acc0 = 3.0e38f, acc1 = 3.0e38f, acc2 = 3.0e38f, acc3 = 3.0e38f;
    float acc4 = 3.0e38f, acc5 = 3.0e38f, acc6 = 3.0e38f, acc7 = 3.0e38f;

    uint4 pipe[DEPTH];
    #pragma unroll
    for (int i = 0; i < DEPTH; ++i) pipe[i] = wp[i * 64];

    // R8-proven shape: rotating DEPTH=4 ring, outer loop NOT unrolled.
    // 2-chain MFMA pipeline: only dA,dB (32 VGPRs) live at once.
    for (int t = 0; t < TILES_PER_WAVE; t += DEPTH) {
        #pragma unroll
        for (int u = 0; u < DEPTH; ++u) {
            uint4 cur = pipe[u];
            // Tail prefetch overreads into resT region: valid memory, never used.
            pipe[u] = wp[(t + u + DEPTH) * 64];
            bf16x8 aop = __builtin_bit_cast(bf16x8, cur);
            f32x16 dA = __builtin_amdgcn_mfma_f32_32x32x16_bf16(aop, res0, zf, 0, 0, 0);
            f32x16 dB = __builtin_amdgcn_mfma_f32_32x32x16_bf16(aop, res1, zf, 0, 0, 0);
            acc0 = tree16acc(dA, acc0);
            dA = __builtin_amdgcn_mfma_f32_32x32x16_bf16(aop, res2, zf, 0, 0, 0);
            acc1 = tree16acc(dB, acc1);
            dB = __builtin_amdgcn_mfma_f32_32x32x16_bf16(aop, res3, zf, 0, 0, 0);
            acc2 = tree16acc(dA, acc2);
            dA = __builtin_amdgcn_mfma_f32_32x32x16_bf16(aop, res4, zf, 0, 0, 0);
            acc3 = tree16acc(dB, acc3);
            dB = __builtin_amdgcn_mfma_f32_32x32x16_bf16(aop, res5, zf, 0, 0, 0);
            acc4 = tree16acc(dA, acc4);
            dA = __builtin_amdgcn_mfma_f32_32x32x16_bf16(aop, res6, zf, 0, 0, 0);
            acc5 = tree16acc(dB, acc5);
            dB = __builtin_amdgcn_mfma_f32_32x32x16_bf16(aop, res7, zf, 0, 0, 0);
            acc6 = tree16acc(dA, acc6);
            acc7 = tree16acc(dB, acc7);
        }
    }

    // Fold lh halves (lane and lane^32 hold complementary stream rows of the
    // same resident col); cross-wave LDS merge (R13-proven epilogue); one
    // coalesced plain store per block into this split's slice. No atomics.
    float accs[FRAGS] = {acc0, acc1, acc2, acc3, acc4, acc5, acc6, acc7};
    #pragma unroll
    for (int f = 0; f < FRAGS; ++f)
        accs[f] = fminf(accs[f], __shfl_xor(accs[f], 32, 64));

    __shared__ float part[4][ROWS_PER_BLK];
    if (lh == 0) {
        #pragma unroll
        for (int f = 0; f < FRAGS; ++f) part[wave][f * 32 + l31] = accs[f];
    }
    __syncthreads();
    int tid = threadIdx.x;
    float m = fminf(fminf(part[0][tid], part[1][tid]),
                    fminf(part[2][tid], part[3][tid]));
    unsigned int* wout = ws_min + (size_t)split * NROWS
                       + (size_t)(dir * NB + batch) * NPTS + rowblk * ROWS_PER_BLK;
    wout[tid] = __float_as_uint(fmaxf(m, 0.0f));
}

__global__ __launch_bounds__(256)
void chamfer_reduce_kernel(const unsigned int* __restrict__ ws_min,
                           float* __restrict__ out) {
    constexpr float SCALE = 1.0f / (NB * NPTS * 12.8f);
    int idx = (blockIdx.x * 256 + threadIdx.x) * 4;
    uint4 v0 = *(const uint4*)(ws_min + idx);
    uint4 v1 = *(const uint4*)(ws_min + 1 * NROWS + idx);
    uint4 v2 = *(const uint4*)(ws_min + 2 * NROWS + idx);
    uint4 v3 = *(const uint4*)(ws_min + 3 * NROWS + idx);
    float mx = fminf(fminf(__uint_as_float(v0.x), __uint_as_float(v1.x)),
                     fminf(__uint_as_float(v2.x), __uint_as_float(v3.x)));
    float my = fminf(fminf(__uint_as_float(v0.y), __uint_as_float(v1.y)),
                     fminf(__uint_as_float(v2.y), __uint_as_float(v3.y)));
    float mz = fminf(fminf(__uint_as_float(v0.z), __uint_as_float(v1.z)),
                     fminf(__uint_as_float(v2.z), __uint_as_float(v3.z)));
    float mw = fminf(fminf(__uint_as_float(v0.w), __uint_as_float(v1.w)),
                     fminf(__uint_as_float(v2.w), __uint_as_float(v3.w)));
    float s = sqrtf(mx) + sqrtf(my) + sqrtf(mz) + sqrtf(mw);
    #pragma unroll
    for (int off = 32; off >= 1; off >>= 1) s += __shfl_down(s, off, 64);
    __shared__ float redl[4];
    if ((threadIdx.x & 63) == 0) redl[threadIdx.x >> 6] = s;
    __syncthreads();
    if (threadIdx.x == 0)
        atomicAdd(out, (redl[0] + redl[1] + redl[2] + redl[3]) * SCALE);
}

extern "C" void kernel_launch(void* const* d_in, const int* in_sizes, int n_in,
                              void* d_out, int out_size, void* d_ws, size_t ws_size,
                              hipStream_t stream) {
    const float* A = (const float*)d_in[0];
    const float* B = (const float*)d_in[1];
    float* out = (float*)d_out;
    u16* streamT = (u16*)d_ws;
    u16* resT = (u16*)((char*)d_ws + REST_OFF);
    unsigned int* wsm = (unsigned int*)((char*)d_ws + WSMIN_OFF);

    chamfer_prep_kernel<<<NROWS / 256, 256, 0, stream>>>(A, B, streamT, resT, out);
    chamfer_minmfma_kernel<<<2 * NB * ROWBLKS * SSPLIT, 256, 0, stream>>>(streamT, resT, wsm);
    chamfer_reduce_kernel<<<NROWS / 4 / 256, 256, 0, stream>>>(wsm, out);
}